// Round 2
// baseline (527.609 us; speedup 1.0000x reference)
//
#include <hip/hip_runtime.h>

// Shapes from the reference:
//   action [B=128, A=256] f32, conv_w [E=256, A=256] f32, conv_b [E=256] f32
//   out [B=128, E=256, H=64, W=64] f32  (512 MiB -> store-BW bound, ~85us floor)
#define B_DIM 128
#define A_DIM 256
#define E_DIM 256
#define HW    4096   // 64*64

// Kernel 1: y[b,e] = relu(dot(action[b,:], conv_w[e,:]) + conv_b[e])
// One block per b (128 blocks), one thread per e (256 threads).
__global__ void __launch_bounds__(256) compute_y_kernel(
    const float* __restrict__ action,
    const float* __restrict__ conv_w,
    const float* __restrict__ conv_b,
    float* __restrict__ y)
{
    const int b = blockIdx.x;
    const int e = threadIdx.x;

    __shared__ float act[A_DIM];
    act[e] = action[b * A_DIM + e];   // blockDim.x == A_DIM == 256
    __syncthreads();

    const float4* w4 = reinterpret_cast<const float4*>(conv_w + e * A_DIM);
    const float4* a4 = reinterpret_cast<const float4*>(act);

    float sum = conv_b[e];
    #pragma unroll
    for (int i = 0; i < A_DIM / 4; ++i) {
        float4 w = w4[i];
        float4 a = a4[i];
        sum = fmaf(a.x, w.x, sum);
        sum = fmaf(a.y, w.y, sum);
        sum = fmaf(a.z, w.z, sum);
        sum = fmaf(a.w, w.w, sum);
    }
    y[b * E_DIM + e] = fmaxf(sum, 0.0f);
}

// Kernel 2: broadcast y[b,e] across the HW=4096 spatial positions.
// Output is contiguous per (b,e): out[(b*E+e)*4096 + s]. float4 stores,
// grid-stride. For float4-index i, the source element is y[i >> 10]
// (4096 floats = 1024 float4 per (b,e)) — same address across 1024
// consecutive lanes -> wave broadcast, L1/L2 resident (y is 128 KB).
__global__ void __launch_bounds__(256) broadcast_y_kernel(
    const float* __restrict__ y,
    float4* __restrict__ out,
    int n4)
{
    const int stride = gridDim.x * blockDim.x;
    for (int i = blockIdx.x * blockDim.x + threadIdx.x; i < n4; i += stride) {
        const float v = y[i >> 10];
        out[i] = make_float4(v, v, v, v);
    }
}

extern "C" void kernel_launch(void* const* d_in, const int* in_sizes, int n_in,
                              void* d_out, int out_size, void* d_ws, size_t ws_size,
                              hipStream_t stream) {
    const float* action = (const float*)d_in[0];
    const float* conv_w = (const float*)d_in[1];
    const float* conv_b = (const float*)d_in[2];
    float* out = (float*)d_out;
    float* y   = (float*)d_ws;   // needs B*E*4 = 128 KiB scratch

    compute_y_kernel<<<B_DIM, 256, 0, stream>>>(action, conv_w, conv_b, y);

    const int n4 = (B_DIM * E_DIM * HW) / 4;   // 33,554,432 float4 stores
    const int block = 256;
    const int grid = 8192;                      // grid-stride: 16 iters/thread
    broadcast_y_kernel<<<grid, block, 0, stream>>>(
        y, reinterpret_cast<float4*>(out), n4);
}

// Round 4
// 526.423 us; speedup vs baseline: 1.0023x; 1.0023x over previous
//
#include <hip/hip_runtime.h>

// Shapes from the reference:
//   action [B=128, A=256] f32, conv_w [E=256, A=256] f32, conv_b [E=256] f32
//   out [B=128, E=256, H=64, W=64] f32  (512 MiB -> store-BW bound, ~85us floor)
#define B_DIM 128
#define A_DIM 256
#define E_DIM 256
#define HW    4096   // 64*64

// Native vector type — __builtin_nontemporal_store rejects HIP_vector_type.
typedef float f32x4 __attribute__((ext_vector_type(4)));

// Kernel 1: y[b,e] = relu(dot(action[b,:], conv_w[e,:]) + conv_b[e])
// One block per b (128 blocks), one thread per e (256 threads). ~2us total.
__global__ void __launch_bounds__(256) compute_y_kernel(
    const float* __restrict__ action,
    const float* __restrict__ conv_w,
    const float* __restrict__ conv_b,
    float* __restrict__ y)
{
    const int b = blockIdx.x;
    const int e = threadIdx.x;

    __shared__ float act[A_DIM];
    act[e] = action[b * A_DIM + e];   // blockDim.x == A_DIM == 256
    __syncthreads();

    const float4* w4 = reinterpret_cast<const float4*>(conv_w + e * A_DIM);
    const float4* a4 = reinterpret_cast<const float4*>(act);

    float sum = conv_b[e];
    #pragma unroll
    for (int i = 0; i < A_DIM / 4; ++i) {
        float4 w = w4[i];
        float4 a = a4[i];
        sum = fmaf(a.x, w.x, sum);
        sum = fmaf(a.y, w.y, sum);
        sum = fmaf(a.z, w.z, sum);
        sum = fmaf(a.w, w.w, sum);
    }
    y[b * E_DIM + e] = fmaxf(sum, 0.0f);
}

// Kernel 2: broadcast. One block per (b,e) chunk: 32768 blocks x 256 threads.
// Each chunk is HW=4096 floats = 1024 float4 = 16 KB, contiguous in out.
// One uniform y-load per block (L1/L2 broadcast), then each thread emits
// 4 non-temporal 16B stores at stride 256 float4 -> each iteration the block
// writes one contiguous 4 KB segment. NT stores bypass L2 (streaming write),
// and there is no loop-carried load dependence.
__global__ void __launch_bounds__(256) broadcast_y_kernel(
    const float* __restrict__ y,
    f32x4* __restrict__ out)
{
    const int chunk = blockIdx.x;              // b*E + e
    const float v = y[chunk];
    const f32x4 v4 = {v, v, v, v};

    f32x4* dst = out + (size_t)chunk * (HW / 4) + threadIdx.x;
    #pragma unroll
    for (int j = 0; j < 4; ++j) {
        __builtin_nontemporal_store(v4, dst + j * 256);
    }
}

extern "C" void kernel_launch(void* const* d_in, const int* in_sizes, int n_in,
                              void* d_out, int out_size, void* d_ws, size_t ws_size,
                              hipStream_t stream) {
    const float* action = (const float*)d_in[0];
    const float* conv_w = (const float*)d_in[1];
    const float* conv_b = (const float*)d_in[2];
    float* out = (float*)d_out;
    float* y   = (float*)d_ws;   // needs B*E*4 = 128 KiB scratch

    compute_y_kernel<<<B_DIM, 256, 0, stream>>>(action, conv_w, conv_b, y);

    broadcast_y_kernel<<<B_DIM * E_DIM, 256, 0, stream>>>(
        y, reinterpret_cast<f32x4*>(out));
}